// Round 2
// baseline (218.941 us; speedup 1.0000x reference)
//
#include <hip/hip_runtime.h>
#include <math.h>

#define U 8192
#define NITEMS 100000
#define H 50
#define QD 128
#define D 256
#define BMG 16     // rows per block in the thin GEMMs (grid = U/BMG = 512)

// broadcast block-reduce (256 threads = 4 waves)
__device__ __forceinline__ float block_reduce_256(float v, float* sred) {
    #pragma unroll
    for (int off = 32; off >= 1; off >>= 1)
        v += __shfl_xor(v, off, 64);
    int wave = threadIdx.x >> 6;
    int lane = threadIdx.x & 63;
    if (lane == 0) sred[wave] = v;
    __syncthreads();
    float s;
    if (threadIdx.x == 0) {
        s = sred[0] + sred[1] + sred[2] + sred[3];
        sred[0] = s;
    }
    __syncthreads();
    s = sred[0];
    __syncthreads();
    return s;
}

// Kernel A: M = Wq @ Wk^T [QD,D]; bqt = bq @ Wk^T [D]; wb = Wq @ bk [QD]; c0 = bq.bk
__global__ void __launch_bounds__(256) upa_precompute(
    const float* __restrict__ Wq, const float* __restrict__ bq,
    const float* __restrict__ Wk, const float* __restrict__ bk,
    float* __restrict__ M, float* __restrict__ bqt,
    float* __restrict__ wb, float* __restrict__ c0) {
    __shared__ float row[D];
    __shared__ float sred[4];
    int k = blockIdx.x;
    int t = threadIdx.x;
    if (k < QD) {
        row[t] = (t < D) ? Wq[k * D + t] : 0.f;
        __syncthreads();
        const float4* wkr = (const float4*)(Wk + (size_t)t * D);
        const float4* rr  = (const float4*)row;
        float acc = 0.f;
        #pragma unroll 4
        for (int i = 0; i < D / 4; ++i) {
            float4 a = rr[i]; float4 b = wkr[i];
            acc += a.x * b.x + a.y * b.y + a.z * b.z + a.w * b.w;
        }
        M[k * D + t] = acc;
        float p = row[t] * bk[t];
        float s = block_reduce_256(p, sred);
        if (t == 0) wb[k] = s;
    } else {
        row[t] = bq[t];
        __syncthreads();
        const float4* wkr = (const float4*)(Wk + (size_t)t * D);
        const float4* rr  = (const float4*)row;
        float acc = 0.f;
        #pragma unroll 4
        for (int i = 0; i < D / 4; ++i) {
            float4 a = rr[i]; float4 b = wkr[i];
            acc += a.x * b.x + a.y * b.y + a.z * b.z + a.w * b.w;
        }
        bqt[t] = acc;
        float p = row[t] * bk[t];
        float s = block_reduce_256(p, sred);
        if (t == 0) c0[0] = s;
    }
}

// Kernel B: qt = uq @ M + bqt   [U,D], K=QD. 16 rows/block, K unrolled by 8.
// A-tile values are wave-uniform on read (LDS broadcast), M reads coalesced.
__global__ void __launch_bounds__(256) upa_qt(
    const float* __restrict__ uq, const float* __restrict__ M,
    const float* __restrict__ bqt, float* __restrict__ qt) {
    __shared__ float A[BMG][QD];   // 8 KB
    int u0 = blockIdx.x * BMG;
    int t = threadIdx.x;
    const float4* src = (const float4*)(uq + (size_t)u0 * QD);
    float4* dst = (float4*)&A[0][0];
    for (int i = t; i < BMG * QD / 4; i += 256) dst[i] = src[i];
    __syncthreads();
    float acc[BMG];
    #pragma unroll
    for (int r = 0; r < BMG; ++r) acc[r] = 0.f;
    for (int k8 = 0; k8 < QD; k8 += 8) {
        float m[8];
        #pragma unroll
        for (int i = 0; i < 8; ++i) m[i] = M[(size_t)(k8 + i) * D + t];
        #pragma unroll
        for (int r = 0; r < BMG; ++r) {
            float4 a0 = *((const float4*)&A[r][k8]);
            float4 a1 = *((const float4*)&A[r][k8 + 4]);
            acc[r] += a0.x * m[0] + a0.y * m[1] + a0.z * m[2] + a0.w * m[3]
                    + a1.x * m[4] + a1.y * m[5] + a1.z * m[6] + a1.w * m[7];
        }
    }
    float bb = bqt[t];
    #pragma unroll
    for (int r = 0; r < BMG; ++r) qt[(size_t)(u0 + r) * D + t] = acc[r] + bb;
}

// Kernel C: one WAVE per user, zero LDS, zero __syncthreads.
// Single-pass streaming identity:
//   w_j = exp(s_j)/ (sum_k exp(s_k) + 1e-12*exp(S)),  S = sum_k s_k
// Per row: gather (scalar base via v_readlane -> SGPR), dot, butterfly
// reduce, exp, FMA into acc. Chunks of 5 rows keep ~5 gathers in flight
// while staying under 64 VGPR for full occupancy.
__global__ void __launch_bounds__(256, 8) upa_attn(
    const float* __restrict__ qt, const float* __restrict__ uq,
    const float* __restrict__ wb, const float* __restrict__ c0,
    const float* __restrict__ feats, const int* __restrict__ item_idx,
    float* __restrict__ agg, float* __restrict__ sw) {
    int wave = threadIdx.x >> 6, lane = threadIdx.x & 63;
    int u = blockIdx.x * 4 + wave;

    // qb = uq[u,:] . wb + c0   (wave-local butterfly)
    float p = uq[(size_t)u * QD + lane] * wb[lane]
            + uq[(size_t)u * QD + 64 + lane] * wb[64 + lane];
    #pragma unroll
    for (int off = 32; off >= 1; off >>= 1)
        p += __shfl_xor(p, off, 64);
    float qb = p + c0[0];

    // full qt row in one b128 per lane
    float4 q = ((const float4*)(qt + (size_t)u * D))[lane];

    // all 50 indices live in lanes 0..49; broadcast later via v_readlane
    int ll = lane < H ? lane : H - 1;
    int idxv = item_idx[(size_t)u * H + ll];

    float4 acc = make_float4(0.f, 0.f, 0.f, 0.f);
    float E = 0.f, S = 0.f;
    #pragma unroll
    for (int c = 0; c < 10; ++c) {
        float4 v[5];
        #pragma unroll
        for (int r = 0; r < 5; ++r) {
            int j = c * 5 + r;                       // compile-time after unroll
            int sidx = __builtin_amdgcn_readlane(idxv, j);  // SGPR base
            v[r] = ((const float4*)(feats + (size_t)sidx * D))[lane];
        }
        #pragma unroll
        for (int r = 0; r < 5; ++r) {
            float part = v[r].x * q.x + v[r].y * q.y + v[r].z * q.z + v[r].w * q.w;
            #pragma unroll
            for (int off = 32; off >= 1; off >>= 1)
                part += __shfl_xor(part, off, 64);
            float s = part + qb;
            float e = __expf(s);
            S += s;
            E += e;
            acc.x += e * v[r].x;
            acc.y += e * v[r].y;
            acc.z += e * v[r].z;
            acc.w += e * v[r].w;
        }
    }

    float inv = 1.f / (E + 1e-12f * __expf(S));
    float4 o = make_float4(acc.x * inv, acc.y * inv, acc.z * inv, acc.w * inv);
    ((float4*)(agg + (size_t)u * D))[lane] = o;
    if (lane == 0) sw[u] = E * inv;
}

// Kernel D: out = agg @ Wv + bv * sw[u]   [U,D], K=D. 16 rows/block.
__global__ void __launch_bounds__(256) upa_out(
    const float* __restrict__ agg, const float* __restrict__ Wv,
    const float* __restrict__ bv, const float* __restrict__ sw,
    float* __restrict__ out) {
    __shared__ float A[BMG][D];    // 16 KB
    int u0 = blockIdx.x * BMG;
    int t = threadIdx.x;
    const float4* src = (const float4*)(agg + (size_t)u0 * D);
    float4* dst = (float4*)&A[0][0];
    for (int i = t; i < BMG * D / 4; i += 256) dst[i] = src[i];
    __syncthreads();
    float acc[BMG];
    #pragma unroll
    for (int r = 0; r < BMG; ++r) acc[r] = 0.f;
    for (int k8 = 0; k8 < D; k8 += 8) {
        float m[8];
        #pragma unroll
        for (int i = 0; i < 8; ++i) m[i] = Wv[(size_t)(k8 + i) * D + t];
        #pragma unroll
        for (int r = 0; r < BMG; ++r) {
            float4 a0 = *((const float4*)&A[r][k8]);
            float4 a1 = *((const float4*)&A[r][k8 + 4]);
            acc[r] += a0.x * m[0] + a0.y * m[1] + a0.z * m[2] + a0.w * m[3]
                    + a1.x * m[4] + a1.y * m[5] + a1.z * m[6] + a1.w * m[7];
        }
    }
    float b = bv[t];
    #pragma unroll
    for (int r = 0; r < BMG; ++r)
        out[(size_t)(u0 + r) * D + t] = acc[r] + b * sw[u0 + r];
}

extern "C" void kernel_launch(void* const* d_in, const int* in_sizes, int n_in,
                              void* d_out, int out_size, void* d_ws, size_t ws_size,
                              hipStream_t stream) {
    const float* uq    = (const float*)d_in[0];   // [U,QD]
    const float* feats = (const float*)d_in[1];   // [N,D]
    const float* Wq    = (const float*)d_in[2];   // [QD,D]
    const float* bq    = (const float*)d_in[3];   // [D]
    const float* Wk    = (const float*)d_in[4];   // [D,D]
    const float* bk    = (const float*)d_in[5];   // [D]
    const float* Wv    = (const float*)d_in[6];   // [D,D]
    const float* bv    = (const float*)d_in[7];   // [D]
    // d_in[8] = batch_user_indices: structurally repeat(arange(U),H) -> implicit
    const int* item_idx = (const int*)d_in[9];    // [E]
    float* out = (float*)d_out;

    float* ws  = (float*)d_ws;
    float* M   = ws;                    // QD*D   = 32768
    float* bqt = M + QD * D;            // D      = 256
    float* wb  = bqt + D;               // QD     = 128
    float* c0  = wb + QD;               // 4 (padded)
    float* qt  = c0 + 4;                // U*D    = 2097152
    float* agg = qt + (size_t)U * D;    // U*D    = 2097152
    float* sw  = agg + (size_t)U * D;   // U      = 8192

    upa_precompute<<<QD + 1, 256, 0, stream>>>(Wq, bq, Wk, bk, M, bqt, wb, c0);
    upa_qt<<<U / BMG, 256, 0, stream>>>(uq, M, bqt, qt);
    upa_attn<<<U / 4, 256, 0, stream>>>(qt, uq, wb, c0, feats, item_idx, agg, sw);
    upa_out<<<U / BMG, 256, 0, stream>>>(agg, Wv, bv, sw, out);
}

// Round 3
// 148.664 us; speedup vs baseline: 1.4727x; 1.4727x over previous
//
#include <hip/hip_runtime.h>
#include <math.h>

#define U 8192
#define NITEMS 100000
#define H 50
#define QD 128
#define D 256
#define BMG 16     // rows per block in the thin GEMMs (grid = U/BMG = 512)
#define NRW 13     // rows per wave in attn (waves 0-2: 13, wave 3: 11 + 2 masked)

// broadcast block-reduce (256 threads = 4 waves)
__device__ __forceinline__ float block_reduce_256(float v, float* sred) {
    #pragma unroll
    for (int off = 32; off >= 1; off >>= 1)
        v += __shfl_xor(v, off, 64);
    int wave = threadIdx.x >> 6;
    int lane = threadIdx.x & 63;
    if (lane == 0) sred[wave] = v;
    __syncthreads();
    float s;
    if (threadIdx.x == 0) {
        s = sred[0] + sred[1] + sred[2] + sred[3];
        sred[0] = s;
    }
    __syncthreads();
    s = sred[0];
    __syncthreads();
    return s;
}

// Kernel A: M = Wq @ Wk^T [QD,D]; bqt = bq @ Wk^T [D]; wb = Wq @ bk [QD]; c0 = bq.bk
__global__ void __launch_bounds__(256) upa_precompute(
    const float* __restrict__ Wq, const float* __restrict__ bq,
    const float* __restrict__ Wk, const float* __restrict__ bk,
    float* __restrict__ M, float* __restrict__ bqt,
    float* __restrict__ wb, float* __restrict__ c0) {
    __shared__ float row[D];
    __shared__ float sred[4];
    int k = blockIdx.x;
    int t = threadIdx.x;
    if (k < QD) {
        row[t] = (t < D) ? Wq[k * D + t] : 0.f;
        __syncthreads();
        const float4* wkr = (const float4*)(Wk + (size_t)t * D);
        const float4* rr  = (const float4*)row;
        float acc = 0.f;
        #pragma unroll 4
        for (int i = 0; i < D / 4; ++i) {
            float4 a = rr[i]; float4 b = wkr[i];
            acc += a.x * b.x + a.y * b.y + a.z * b.z + a.w * b.w;
        }
        M[k * D + t] = acc;
        float p = row[t] * bk[t];
        float s = block_reduce_256(p, sred);
        if (t == 0) wb[k] = s;
    } else {
        row[t] = bq[t];
        __syncthreads();
        const float4* wkr = (const float4*)(Wk + (size_t)t * D);
        const float4* rr  = (const float4*)row;
        float acc = 0.f;
        #pragma unroll 4
        for (int i = 0; i < D / 4; ++i) {
            float4 a = rr[i]; float4 b = wkr[i];
            acc += a.x * b.x + a.y * b.y + a.z * b.z + a.w * b.w;
        }
        bqt[t] = acc;
        float p = row[t] * bk[t];
        float s = block_reduce_256(p, sred);
        if (t == 0) c0[0] = s;
    }
}

// Kernel B: qt = uq @ M + bqt   [U,D], K=QD. 16 rows/block, K unrolled by 8.
__global__ void __launch_bounds__(256) upa_qt(
    const float* __restrict__ uq, const float* __restrict__ M,
    const float* __restrict__ bqt, float* __restrict__ qt) {
    __shared__ float A[BMG][QD];   // 8 KB
    int u0 = blockIdx.x * BMG;
    int t = threadIdx.x;
    const float4* src = (const float4*)(uq + (size_t)u0 * QD);
    float4* dst = (float4*)&A[0][0];
    for (int i = t; i < BMG * QD / 4; i += 256) dst[i] = src[i];
    __syncthreads();
    float acc[BMG];
    #pragma unroll
    for (int r = 0; r < BMG; ++r) acc[r] = 0.f;
    for (int k8 = 0; k8 < QD; k8 += 8) {
        float m[8];
        #pragma unroll
        for (int i = 0; i < 8; ++i) m[i] = M[(size_t)(k8 + i) * D + t];
        #pragma unroll
        for (int r = 0; r < BMG; ++r) {
            float4 a0 = *((const float4*)&A[r][k8]);
            float4 a1 = *((const float4*)&A[r][k8 + 4]);
            acc[r] += a0.x * m[0] + a0.y * m[1] + a0.z * m[2] + a0.w * m[3]
                    + a1.x * m[4] + a1.y * m[5] + a1.z * m[6] + a1.w * m[7];
        }
    }
    float bb = bqt[t];
    #pragma unroll
    for (int r = 0; r < BMG; ++r) qt[(size_t)(u0 + r) * D + t] = acc[r] + bb;
}

// Kernel C: 4 waves per user, SINGLE-PASS streaming, each feats row loaded by
// exactly ONE b128 per lane. Rows assigned contiguously: wave w owns rows
// [w*13, w*13+13) (wave 3: last 2 masked). Double-buffered 4-row register
// chunks keep 4-8 gathers in flight per wave while chunk c is consumed.
// Identity (verified r1/r2, absmax unchanged):
//   w_j = exp(s_j)/(sum_k exp(s_k) + 1e-12*exp(S)),  S = sum_k s_k
__global__ void __launch_bounds__(256, 6) upa_attn(
    const float* __restrict__ qt, const float* __restrict__ uq,
    const float* __restrict__ wb, const float* __restrict__ c0,
    const float* __restrict__ feats, const int* __restrict__ item_idx,
    float* __restrict__ agg, float* __restrict__ sw) {
    __shared__ float pagg[4][D];    // 4 KB cross-wave partials
    __shared__ float pE[4], pS[4];
    int u = blockIdx.x;
    int t = threadIdx.x;
    int wave = t >> 6, lane = t & 63;

    // per-wave qb = uq[u,:].wb + c0 (redundant across waves, no barrier needed)
    float p = uq[(size_t)u * QD + lane] * wb[lane]
            + uq[(size_t)u * QD + 64 + lane] * wb[64 + lane];
    #pragma unroll
    for (int off = 32; off >= 1; off >>= 1)
        p += __shfl_xor(p, off, 64);
    float qb = p + c0[0];

    // full qt row in one b128 per lane
    float4 q = ((const float4*)(qt + (size_t)u * D))[lane];

    // all 50 indices in lanes 0..49 of idxv; broadcast via v_readlane (SGPR base)
    int ll = lane < H ? lane : H - 1;
    int idxv = item_idx[(size_t)u * H + ll];

    int base = wave * NRW;              // 0,13,26,39 (wave-uniform)

    float4 vc[4], vn[4];
    #pragma unroll
    for (int r = 0; r < 4; ++r) {
        int j = base + r;
        int jj = j < H ? j : H - 1;     // scalar clamp (dup load hits L1)
        int sidx = __builtin_amdgcn_readlane(idxv, jj);
        vc[r] = ((const float4*)(feats + (size_t)sidx * D))[lane];
    }

    float4 acc = make_float4(0.f, 0.f, 0.f, 0.f);
    float E = 0.f, S = 0.f;
    #pragma unroll
    for (int c = 0; c < 4; ++c) {
        // prefetch next chunk (chunk 3 prefetches nothing real; guard below)
        if (c < 3) {
            #pragma unroll
            for (int r = 0; r < 4; ++r) {
                int j = base + (c + 1) * 4 + r;
                int jj = j < H ? j : H - 1;
                int sidx = __builtin_amdgcn_readlane(idxv, jj);
                vn[r] = ((const float4*)(feats + (size_t)sidx * D))[lane];
            }
        }
        // consume current chunk
        #pragma unroll
        for (int r = 0; r < 4; ++r) {
            int j = base + c * 4 + r;
            if (c * 4 + r < NRW) {                 // static bound: 13 rows max
                float m = (j < H) ? 1.f : 0.f;     // mask waves-3 tail (j=50,51)
                float part = vc[r].x * q.x + vc[r].y * q.y
                           + vc[r].z * q.z + vc[r].w * q.w;
                #pragma unroll
                for (int off = 32; off >= 1; off >>= 1)
                    part += __shfl_xor(part, off, 64);
                float s = (part + qb) * m;
                float e = __expf(part + qb) * m;
                S += s;
                E += e;
                acc.x += e * vc[r].x;
                acc.y += e * vc[r].y;
                acc.z += e * vc[r].z;
                acc.w += e * vc[r].w;
            }
        }
        #pragma unroll
        for (int r = 0; r < 4; ++r) vc[r] = vn[r];  // SSA-renamed, no real moves
    }

    // cross-wave combine (single barrier in the whole kernel)
    ((float4*)pagg[wave])[lane] = acc;
    if (lane == 0) { pE[wave] = E; pS[wave] = S; }
    __syncthreads();
    float Et = pE[0] + pE[1] + pE[2] + pE[3];
    float St = pS[0] + pS[1] + pS[2] + pS[3];
    float inv = 1.f / (Et + 1e-12f * __expf(St));
    agg[(size_t)u * D + t] =
        (pagg[0][t] + pagg[1][t] + pagg[2][t] + pagg[3][t]) * inv;
    if (t == 0) sw[u] = Et * inv;
}

// Kernel D: out = agg @ Wv + bv * sw[u]   [U,D], K=D. 16 rows/block.
__global__ void __launch_bounds__(256) upa_out(
    const float* __restrict__ agg, const float* __restrict__ Wv,
    const float* __restrict__ bv, const float* __restrict__ sw,
    float* __restrict__ out) {
    __shared__ float A[BMG][D];    // 16 KB
    int u0 = blockIdx.x * BMG;
    int t = threadIdx.x;
    const float4* src = (const float4*)(agg + (size_t)u0 * D);
    float4* dst = (float4*)&A[0][0];
    for (int i = t; i < BMG * D / 4; i += 256) dst[i] = src[i];
    __syncthreads();
    float acc[BMG];
    #pragma unroll
    for (int r = 0; r < BMG; ++r) acc[r] = 0.f;
    for (int k8 = 0; k8 < D; k8 += 8) {
        float m[8];
        #pragma unroll
        for (int i = 0; i < 8; ++i) m[i] = Wv[(size_t)(k8 + i) * D + t];
        #pragma unroll
        for (int r = 0; r < BMG; ++r) {
            float4 a0 = *((const float4*)&A[r][k8]);
            float4 a1 = *((const float4*)&A[r][k8 + 4]);
            acc[r] += a0.x * m[0] + a0.y * m[1] + a0.z * m[2] + a0.w * m[3]
                    + a1.x * m[4] + a1.y * m[5] + a1.z * m[6] + a1.w * m[7];
        }
    }
    float b = bv[t];
    #pragma unroll
    for (int r = 0; r < BMG; ++r)
        out[(size_t)(u0 + r) * D + t] = acc[r] + b * sw[u0 + r];
}

extern "C" void kernel_launch(void* const* d_in, const int* in_sizes, int n_in,
                              void* d_out, int out_size, void* d_ws, size_t ws_size,
                              hipStream_t stream) {
    const float* uq    = (const float*)d_in[0];   // [U,QD]
    const float* feats = (const float*)d_in[1];   // [N,D]
    const float* Wq    = (const float*)d_in[2];   // [QD,D]
    const float* bq    = (const float*)d_in[3];   // [D]
    const float* Wk    = (const float*)d_in[4];   // [D,D]
    const float* bk    = (const float*)d_in[5];   // [D]
    const float* Wv    = (const float*)d_in[6];   // [D,D]
    const float* bv    = (const float*)d_in[7];   // [D]
    // d_in[8] = batch_user_indices: structurally repeat(arange(U),H) -> implicit
    const int* item_idx = (const int*)d_in[9];    // [E]
    float* out = (float*)d_out;

    float* ws  = (float*)d_ws;
    float* M   = ws;                    // QD*D   = 32768
    float* bqt = M + QD * D;            // D      = 256
    float* wb  = bqt + D;               // QD     = 128
    float* c0  = wb + QD;               // 4 (padded)
    float* qt  = c0 + 4;                // U*D    = 2097152
    float* agg = qt + (size_t)U * D;    // U*D    = 2097152
    float* sw  = agg + (size_t)U * D;   // U      = 8192

    upa_precompute<<<QD + 1, 256, 0, stream>>>(Wq, bq, Wk, bk, M, bqt, wb, c0);
    upa_qt<<<U / BMG, 256, 0, stream>>>(uq, M, bqt, qt);
    upa_attn<<<U, 256, 0, stream>>>(qt, uq, wb, c0, feats, item_idx, agg, sw);
    upa_out<<<U / BMG, 256, 0, stream>>>(agg, Wv, bv, sw, out);
}